// Round 2
// baseline (1743.462 us; speedup 1.0000x reference)
//
#include <hip/hip_runtime.h>
#include <hip/hip_bf16.h>

// Problem constants (from reference)
constexpr int B = 16;
constexpr int N = 8192;
constexpr int H = 768;
constexpr int Q = 32;      // K_SEEDS
constexpr int K = 128;     // TOPK
#define SCALE 0.28867513459481287f   // 12^-0.5

// ---------------------------------------------------------------------------
// Kernel 1: scores[b*Q+q][n] = dot(input[b,n,:], seed[q,:])
// Grid 256 blocks x 512 threads; 1 block/CU (96 KiB LDS). Per wave: 8 rows x
// 8 q (qg octet) in registers; explicit 2-stage SW pipeline over h-chunks.
// ---------------------------------------------------------------------------
__global__ __launch_bounds__(512, 2) void k_scores(const float* __restrict__ x,
                                                   const float* __restrict__ seed,
                                                   float* __restrict__ scores) {
  __shared__ __align__(16) float s_seed[Q * H];   // 96 KiB
  for (int i = threadIdx.x; i < Q * H / 4; i += 512)
    reinterpret_cast<float4*>(s_seed)[i] = reinterpret_cast<const float4*>(seed)[i];
  __syncthreads();

  const int wave = threadIdx.x >> 6;
  const int lane = threadIdx.x & 63;
  const int hg = lane & 15;
  const int qg = lane >> 4;

  float4 xa[8], xb[8];
  float acc[8][8];

  // Prologue: chunk 0 of it=0.
  {
    const float* xp0 = x + (size_t)((blockIdx.x << 9) + (wave << 3)) * H;
#pragma unroll
    for (int r = 0; r < 8; ++r)
      xa[r] = *reinterpret_cast<const float4*>(xp0 + r * H + (hg << 2));
  }

  for (int it = 0; it < 8; ++it) {
    const int row0 = (blockIdx.x << 9) + (it << 6) + (wave << 3);  // 8 rows
    const float* xp = x + (size_t)row0 * H;

#pragma unroll
    for (int r = 0; r < 8; ++r)
#pragma unroll
      for (int j = 0; j < 8; ++j) acc[r][j] = 0.f;

    auto compute = [&](int c, const float4 (&xv)[8]) {
#pragma unroll
      for (int j = 0; j < 8; ++j) {
        const float4 sv = *reinterpret_cast<const float4*>(
            &s_seed[(qg * 8 + j) * H + (c << 6) + (hg << 2)]);
#pragma unroll
        for (int r = 0; r < 8; ++r) {
          acc[r][j] = fmaf(xv[r].x, sv.x, acc[r][j]);
          acc[r][j] = fmaf(xv[r].y, sv.y, acc[r][j]);
          acc[r][j] = fmaf(xv[r].z, sv.z, acc[r][j]);
          acc[r][j] = fmaf(xv[r].w, sv.w, acc[r][j]);
        }
      }
    };

#pragma unroll
    for (int cc = 0; cc < 12; cc += 2) {
      const int h1 = ((cc + 1) << 6) + (hg << 2);
#pragma unroll
      for (int r = 0; r < 8; ++r)
        xb[r] = *reinterpret_cast<const float4*>(xp + r * H + h1);

      compute(cc, xa);

      if (cc + 2 < 12) {
        const int h2 = ((cc + 2) << 6) + (hg << 2);
#pragma unroll
        for (int r = 0; r < 8; ++r)
          xa[r] = *reinterpret_cast<const float4*>(xp + r * H + h2);
      } else if (it < 7) {
        const float* xn = xp + (size_t)64 * H;   // next it, chunk 0
#pragma unroll
        for (int r = 0; r < 8; ++r)
          xa[r] = *reinterpret_cast<const float4*>(xn + r * H + (hg << 2));
      }

      compute(cc + 1, xb);
    }

    // Value-splitting butterfly reduce across the 16 hg lanes.
    const bool up8 = (hg & 8) != 0;
    const bool up4 = (hg & 4) != 0;
    const bool up2 = (hg & 2) != 0;
    const bool up1 = (hg & 1) != 0;

    float t8[8][4];
#pragma unroll
    for (int r = 0; r < 8; ++r)
#pragma unroll
      for (int jj = 0; jj < 4; ++jj) {
        float send = up8 ? acc[r][jj] : acc[r][jj + 4];
        float recv = __shfl_xor(send, 8);
        float keep = up8 ? acc[r][jj + 4] : acc[r][jj];
        t8[r][jj] = keep + recv;
      }
    float t4[8][2];
#pragma unroll
    for (int r = 0; r < 8; ++r)
#pragma unroll
      for (int jj = 0; jj < 2; ++jj) {
        float send = up4 ? t8[r][jj] : t8[r][jj + 2];
        float recv = __shfl_xor(send, 4);
        float keep = up4 ? t8[r][jj + 2] : t8[r][jj];
        t4[r][jj] = keep + recv;
      }
    float t2[8];
#pragma unroll
    for (int r = 0; r < 8; ++r) {
      float send = up2 ? t4[r][0] : t4[r][1];
      float recv = __shfl_xor(send, 2);
      float keep = up2 ? t4[r][1] : t4[r][0];
      t2[r] = keep + recv;
    }
    float v4[4];
#pragma unroll
    for (int k = 0; k < 4; ++k) {
      float send = up1 ? t2[k] : t2[k + 4];
      float recv = __shfl_xor(send, 1);
      float keep = up1 ? t2[k + 4] : t2[k];
      v4[k] = keep + recv;
    }

    const int j = (hg >> 1) & 7;
    const int q = qg * 8 + j;
    const int b = row0 >> 13;
    const int n0 = (row0 & (N - 1)) + ((hg & 1) << 2);
    float4 o;
    o.x = v4[0]; o.y = v4[1]; o.z = v4[2]; o.w = v4[3];
    *reinterpret_cast<float4*>(scores + (((size_t)(b * Q + q)) << 13) + n0) = o;
  }
}

// ---------------------------------------------------------------------------
// Kernel 2: per (b,q) row: top-128 of 8192 scores -> softmax -> gather V.
// Grid 512 blocks x 256 threads.
// ---------------------------------------------------------------------------
__global__ __launch_bounds__(256) void k_topk(const float* __restrict__ scores,
                                              const float* __restrict__ x,
                                              float* __restrict__ out) {
  const int bq = blockIdx.x;
  const int b = bq >> 5;
  const int tid = threadIdx.x;
  const float* srow = scores + ((size_t)bq << 13);

  // Load 32 scores per thread; build monotonic uint keys.
  float f[32];
  uint32_t u[32];
  const float4* s4 = reinterpret_cast<const float4*>(srow);
#pragma unroll
  for (int i = 0; i < 8; ++i) {
    float4 v = s4[i * 256 + tid];
    f[i * 4 + 0] = v.x; f[i * 4 + 1] = v.y;
    f[i * 4 + 2] = v.z; f[i * 4 + 3] = v.w;
  }
#pragma unroll
  for (int e = 0; e < 32; ++e) {
    uint32_t bits = __float_as_uint(f[e]);
    u[e] = (bits & 0x80000000u) ? ~bits : (bits | 0x80000000u);
  }

  // Binary search smallest T with count(u > T) < K.
  __shared__ int s_red[4];
  uint32_t lo = 0u, hi = 0xFFFFFFFFu;
  while (lo < hi) {
    uint32_t mid = lo + ((hi - lo) >> 1);
    int cnt = 0;
#pragma unroll
    for (int e = 0; e < 32; ++e) cnt += (u[e] > mid) ? 1 : 0;
#pragma unroll
    for (int m = 1; m < 64; m <<= 1) cnt += __shfl_xor(cnt, m);
    if ((tid & 63) == 0) s_red[tid >> 6] = cnt;
    __syncthreads();
    cnt = s_red[0] + s_red[1] + s_red[2] + s_red[3];
    if (cnt >= K) lo = mid + 1; else hi = mid;
    __syncthreads();
  }
  const uint32_t T = lo;

  // Collect strictly-greater, then lowest-index ties == T.
  __shared__ int s_cnt, s_eqn;
  __shared__ int s_idx[K];
  __shared__ float s_w[K];
  __shared__ int s_eq[256];
  __shared__ float s_m, s_sum;
  if (tid == 0) { s_cnt = 0; s_eqn = 0; }
  __syncthreads();
#pragma unroll
  for (int e = 0; e < 32; ++e) {
    int n = ((e >> 2) << 10) + (tid << 2) + (e & 3);
    if (u[e] > T) {
      int p = atomicAdd(&s_cnt, 1);
      s_idx[p] = n;
      s_w[p] = f[e];
    } else if (u[e] == T) {
      int p = atomicAdd(&s_eqn, 1);
      if (p < 256) s_eq[p] = n;
    }
  }
  __syncthreads();
  const int c1 = s_cnt;
  const int need = K - c1;
  if (tid == 0 && need > 0) {
    uint32_t tb = (T & 0x80000000u) ? (T ^ 0x80000000u) : ~T;
    float tf = __uint_as_float(tb);
    int m = s_eqn; if (m > 256) m = 256;
    for (int a = 0; a < need; ++a) {       // selection-sort lowest indices
      int best = s_eq[a], bi = a;
      for (int z = a + 1; z < m; ++z)
        if (s_eq[z] < best) { best = s_eq[z]; bi = z; }
      s_eq[bi] = s_eq[a]; s_eq[a] = best;
      s_idx[c1 + a] = best;
      s_w[c1 + a] = tf;
    }
  }
  __syncthreads();

  // Softmax over the 128 selected values (store un-normalized exp in s_w).
  if (tid < 64) {
    float v = fmaxf(s_w[tid], s_w[tid + 64]);
#pragma unroll
    for (int m = 1; m < 64; m <<= 1) v = fmaxf(v, __shfl_xor(v, m));
    if (tid == 0) s_m = v;
  }
  __syncthreads();
  const float mx = s_m * SCALE;
  if (tid < K) s_w[tid] = __expf(s_w[tid] * SCALE - mx);
  __syncthreads();
  if (tid < 64) {
    float v = s_w[tid] + s_w[tid + 64];
#pragma unroll
    for (int m = 1; m < 64; m <<= 1) v += __shfl_xor(v, m);
    if (tid == 0) s_sum = v;
  }
  __syncthreads();

  // Gather + weighted sum: all 256 threads, 3 floats each (h = tid, +256, +512).
  {
    const float* xb = x + (((size_t)b) << 13) * H;
    float a0 = 0.f, a1 = 0.f, a2 = 0.f;
#pragma unroll 4
    for (int k = 0; k < K; ++k) {
      const float w = s_w[k];
      const float* vp = xb + (size_t)s_idx[k] * H;
      a0 = fmaf(w, vp[tid],       a0);
      a1 = fmaf(w, vp[tid + 256], a1);
      a2 = fmaf(w, vp[tid + 512], a2);
    }
    const float inv = 1.f / s_sum;
    float* op = out + (size_t)bq * H;
    op[tid]       = a0 * inv;
    op[tid + 256] = a1 * inv;
    op[tid + 512] = a2 * inv;
  }
}

extern "C" void kernel_launch(void* const* d_in, const int* in_sizes, int n_in,
                              void* d_out, int out_size, void* d_ws, size_t ws_size,
                              hipStream_t stream) {
  const float* x = (const float*)d_in[0];     // [B, N, H] f32
  const float* seed = (const float*)d_in[1];  // [1, Q, H] f32
  float* out = (float*)d_out;                 // [B, Q, H] f32
  float* scores = (float*)d_ws;               // [B*Q, N] f32 = 16 MiB scratch

  k_scores<<<256, 512, 0, stream>>>(x, seed, scores);
  k_topk<<<512, 256, 0, stream>>>(scores, x, out);
}

// Round 3
// 166.081 us; speedup vs baseline: 10.4976x; 10.4976x over previous
//
#include <hip/hip_runtime.h>
#include <hip/hip_bf16.h>

// Problem constants (from reference)
constexpr int B = 16;
constexpr int N = 8192;
constexpr int H = 768;
constexpr int Q = 32;      // K_SEEDS
constexpr int K = 128;     // TOPK
#define SCALE 0.28867513459481287f   // 12^-0.5

// ---------------------------------------------------------------------------
// Kernel 1: scores[b*Q+q][n] = dot(input[b,n,:], seed[q,:])
// Grid 256 blocks x 1024 threads; 96 KiB LDS -> 1 block/CU = 4 waves/SIMD.
// Per wave per it: 4 rows x 8 q (qg octet) in registers (acc[4][8] = 32 VGPR).
// No lambdas, no software pipeline: TLP (4 waves/SIMD) hides latency.
// ---------------------------------------------------------------------------
__global__ __launch_bounds__(1024, 4) void k_scores(const float* __restrict__ x,
                                                    const float* __restrict__ seed,
                                                    float* __restrict__ scores) {
  __shared__ __align__(16) float s_seed[Q * H];   // 96 KiB
  for (int i = threadIdx.x; i < Q * H / 4; i += 1024)
    reinterpret_cast<float4*>(s_seed)[i] = reinterpret_cast<const float4*>(seed)[i];
  __syncthreads();

  const int wave = threadIdx.x >> 6;   // 0..15
  const int lane = threadIdx.x & 63;
  const int hg = lane & 15;            // h slice
  const int qg = lane >> 4;            // q octet

  const bool up8 = (hg & 8) != 0;
  const bool up4 = (hg & 4) != 0;
  const bool up2 = (hg & 2) != 0;
  const bool up1 = (hg & 1) != 0;

  for (int it = 0; it < 8; ++it) {
    const int row0 = (blockIdx.x << 9) + (it << 6) + (wave << 2);  // 4 rows
    const float* xp = x + (size_t)row0 * H;

    float acc[4][8];
#pragma unroll
    for (int r = 0; r < 4; ++r)
#pragma unroll
      for (int j = 0; j < 8; ++j) acc[r][j] = 0.f;

#pragma unroll 2
    for (int c = 0; c < 12; ++c) {
      const int h0 = (c << 6) + (hg << 2);
      const float4 xv0 = *reinterpret_cast<const float4*>(xp + 0 * H + h0);
      const float4 xv1 = *reinterpret_cast<const float4*>(xp + 1 * H + h0);
      const float4 xv2 = *reinterpret_cast<const float4*>(xp + 2 * H + h0);
      const float4 xv3 = *reinterpret_cast<const float4*>(xp + 3 * H + h0);
#pragma unroll
      for (int j = 0; j < 8; ++j) {
        const float4 sv =
            *reinterpret_cast<const float4*>(&s_seed[(qg * 8 + j) * H + h0]);
        acc[0][j] = fmaf(xv0.x, sv.x, acc[0][j]);
        acc[0][j] = fmaf(xv0.y, sv.y, acc[0][j]);
        acc[0][j] = fmaf(xv0.z, sv.z, acc[0][j]);
        acc[0][j] = fmaf(xv0.w, sv.w, acc[0][j]);
        acc[1][j] = fmaf(xv1.x, sv.x, acc[1][j]);
        acc[1][j] = fmaf(xv1.y, sv.y, acc[1][j]);
        acc[1][j] = fmaf(xv1.z, sv.z, acc[1][j]);
        acc[1][j] = fmaf(xv1.w, sv.w, acc[1][j]);
        acc[2][j] = fmaf(xv2.x, sv.x, acc[2][j]);
        acc[2][j] = fmaf(xv2.y, sv.y, acc[2][j]);
        acc[2][j] = fmaf(xv2.z, sv.z, acc[2][j]);
        acc[2][j] = fmaf(xv2.w, sv.w, acc[2][j]);
        acc[3][j] = fmaf(xv3.x, sv.x, acc[3][j]);
        acc[3][j] = fmaf(xv3.y, sv.y, acc[3][j]);
        acc[3][j] = fmaf(xv3.z, sv.z, acc[3][j]);
        acc[3][j] = fmaf(xv3.w, sv.w, acc[3][j]);
      }
    }

    // Value-splitting butterfly across the 16 hg lanes (30 shuffles).
    float t8[4][4];
#pragma unroll
    for (int r = 0; r < 4; ++r)
#pragma unroll
      for (int jj = 0; jj < 4; ++jj) {
        float send = up8 ? acc[r][jj] : acc[r][jj + 4];
        float recv = __shfl_xor(send, 8);
        float keep = up8 ? acc[r][jj + 4] : acc[r][jj];
        t8[r][jj] = keep + recv;
      }
    float t4[4][2];
#pragma unroll
    for (int r = 0; r < 4; ++r)
#pragma unroll
      for (int jj = 0; jj < 2; ++jj) {
        float send = up4 ? t8[r][jj] : t8[r][jj + 2];
        float recv = __shfl_xor(send, 4);
        float keep = up4 ? t8[r][jj + 2] : t8[r][jj];
        t4[r][jj] = keep + recv;
      }
    float t2[4];
#pragma unroll
    for (int r = 0; r < 4; ++r) {
      float send = up2 ? t4[r][0] : t4[r][1];
      float recv = __shfl_xor(send, 2);
      float keep = up2 ? t4[r][1] : t4[r][0];
      t2[r] = keep + recv;
    }
    float v2[2];
#pragma unroll
    for (int k = 0; k < 2; ++k) {
      float send = up1 ? t2[k] : t2[k + 2];
      float recv = __shfl_xor(send, 1);
      float keep = up1 ? t2[k + 2] : t2[k];
      v2[k] = keep + recv;
    }

    // Lane hg owns q = qg*8 + ((hg>>1)&7), rows n0..n0+1.
    const int j = (hg >> 1) & 7;
    const int q = qg * 8 + j;
    const int b = row0 >> 13;
    const int n0 = (row0 & (N - 1)) + ((hg & 1) << 1);
    float2 o;
    o.x = v2[0]; o.y = v2[1];
    *reinterpret_cast<float2*>(scores + (((size_t)(b * Q + q)) << 13) + n0) = o;
  }
}

// ---------------------------------------------------------------------------
// Kernel 2: per (b,q) row: top-128 of 8192 scores -> softmax -> gather V.
// Grid 512 blocks x 256 threads.
// ---------------------------------------------------------------------------
__global__ __launch_bounds__(256) void k_topk(const float* __restrict__ scores,
                                              const float* __restrict__ x,
                                              float* __restrict__ out) {
  const int bq = blockIdx.x;
  const int b = bq >> 5;
  const int tid = threadIdx.x;
  const float* srow = scores + ((size_t)bq << 13);

  // Load 32 scores per thread; build monotonic uint keys.
  float f[32];
  uint32_t u[32];
  const float4* s4 = reinterpret_cast<const float4*>(srow);
#pragma unroll
  for (int i = 0; i < 8; ++i) {
    float4 v = s4[i * 256 + tid];
    f[i * 4 + 0] = v.x; f[i * 4 + 1] = v.y;
    f[i * 4 + 2] = v.z; f[i * 4 + 3] = v.w;
  }
#pragma unroll
  for (int e = 0; e < 32; ++e) {
    uint32_t bits = __float_as_uint(f[e]);
    u[e] = (bits & 0x80000000u) ? ~bits : (bits | 0x80000000u);
  }

  // Binary search smallest T with count(u > T) < K.
  __shared__ int s_red[4];
  uint32_t lo = 0u, hi = 0xFFFFFFFFu;
  while (lo < hi) {
    uint32_t mid = lo + ((hi - lo) >> 1);
    int cnt = 0;
#pragma unroll
    for (int e = 0; e < 32; ++e) cnt += (u[e] > mid) ? 1 : 0;
#pragma unroll
    for (int m = 1; m < 64; m <<= 1) cnt += __shfl_xor(cnt, m);
    if ((tid & 63) == 0) s_red[tid >> 6] = cnt;
    __syncthreads();
    cnt = s_red[0] + s_red[1] + s_red[2] + s_red[3];
    if (cnt >= K) lo = mid + 1; else hi = mid;
    __syncthreads();
  }
  const uint32_t T = lo;

  // Collect strictly-greater, then lowest-index ties == T.
  __shared__ int s_cnt, s_eqn;
  __shared__ int s_idx[K];
  __shared__ float s_w[K];
  __shared__ int s_eq[256];
  __shared__ float s_m, s_sum;
  if (tid == 0) { s_cnt = 0; s_eqn = 0; }
  __syncthreads();
#pragma unroll
  for (int e = 0; e < 32; ++e) {
    int n = ((e >> 2) << 10) + (tid << 2) + (e & 3);
    if (u[e] > T) {
      int p = atomicAdd(&s_cnt, 1);
      s_idx[p] = n;
      s_w[p] = f[e];
    } else if (u[e] == T) {
      int p = atomicAdd(&s_eqn, 1);
      if (p < 256) s_eq[p] = n;
    }
  }
  __syncthreads();
  const int c1 = s_cnt;
  const int need = K - c1;
  if (tid == 0 && need > 0) {
    uint32_t tb = (T & 0x80000000u) ? (T ^ 0x80000000u) : ~T;
    float tf = __uint_as_float(tb);
    int m = s_eqn; if (m > 256) m = 256;
    for (int a = 0; a < need; ++a) {       // selection-sort lowest indices
      int best = s_eq[a], bi = a;
      for (int z = a + 1; z < m; ++z)
        if (s_eq[z] < best) { best = s_eq[z]; bi = z; }
      s_eq[bi] = s_eq[a]; s_eq[a] = best;
      s_idx[c1 + a] = best;
      s_w[c1 + a] = tf;
    }
  }
  __syncthreads();

  // Softmax over the 128 selected values (store un-normalized exp in s_w).
  if (tid < 64) {
    float v = fmaxf(s_w[tid], s_w[tid + 64]);
#pragma unroll
    for (int m = 1; m < 64; m <<= 1) v = fmaxf(v, __shfl_xor(v, m));
    if (tid == 0) s_m = v;
  }
  __syncthreads();
  const float mx = s_m * SCALE;
  if (tid < K) s_w[tid] = __expf(s_w[tid] * SCALE - mx);
  __syncthreads();
  if (tid < 64) {
    float v = s_w[tid] + s_w[tid + 64];
#pragma unroll
    for (int m = 1; m < 64; m <<= 1) v += __shfl_xor(v, m);
    if (tid == 0) s_sum = v;
  }
  __syncthreads();

  // Gather + weighted sum: all 256 threads, 3 floats each (h = tid, +256, +512).
  {
    const float* xb = x + (((size_t)b) << 13) * H;
    float a0 = 0.f, a1 = 0.f, a2 = 0.f;
#pragma unroll 4
    for (int k = 0; k < K; ++k) {
      const float w = s_w[k];
      const float* vp = xb + (size_t)s_idx[k] * H;
      a0 = fmaf(w, vp[tid],       a0);
      a1 = fmaf(w, vp[tid + 256], a1);
      a2 = fmaf(w, vp[tid + 512], a2);
    }
    const float inv = 1.f / s_sum;
    float* op = out + (size_t)bq * H;
    op[tid]       = a0 * inv;
    op[tid + 256] = a1 * inv;
    op[tid + 512] = a2 * inv;
  }
}

extern "C" void kernel_launch(void* const* d_in, const int* in_sizes, int n_in,
                              void* d_out, int out_size, void* d_ws, size_t ws_size,
                              hipStream_t stream) {
  const float* x = (const float*)d_in[0];     // [B, N, H] f32
  const float* seed = (const float*)d_in[1];  // [1, Q, H] f32
  float* out = (float*)d_out;                 // [B, Q, H] f32
  float* scores = (float*)d_ws;               // [B*Q, N] f32 = 16 MiB scratch

  k_scores<<<256, 1024, 0, stream>>>(x, seed, scores);
  k_topk<<<512, 256, 0, stream>>>(scores, x, out);
}

// Round 4
// 154.720 us; speedup vs baseline: 11.2685x; 1.0734x over previous
//
#include <hip/hip_runtime.h>
#include <hip/hip_bf16.h>

// Problem constants (from reference)
constexpr int B = 16;
constexpr int N = 8192;
constexpr int H = 768;
constexpr int Q = 32;      // K_SEEDS
constexpr int K = 128;     // TOPK
#define SCALE 0.28867513459481287f   // 12^-0.5

// ---------------------------------------------------------------------------
// Kernel 1 (round-1 known-good): scores[b*Q+q][n] = dot(input[b,n,:], seed[q,:])
// Grid 256 blocks x 512 threads; 96 KiB LDS -> 1 block/CU, 2 waves/SIMD.
// Per wave: 8 rows x 8 q (qg octet) in registers.
// ---------------------------------------------------------------------------
__global__ __launch_bounds__(512, 2) void k_scores(const float* __restrict__ x,
                                                   const float* __restrict__ seed,
                                                   float* __restrict__ scores) {
  __shared__ __align__(16) float s_seed[Q * H];   // 96 KiB
  for (int i = threadIdx.x; i < Q * H / 4; i += 512)
    reinterpret_cast<float4*>(s_seed)[i] = reinterpret_cast<const float4*>(seed)[i];
  __syncthreads();

  const int wave = threadIdx.x >> 6;
  const int lane = threadIdx.x & 63;
  const int hg = lane & 15;
  const int qg = lane >> 4;

  for (int it = 0; it < 8; ++it) {
    const int row0 = (blockIdx.x << 9) + (it << 6) + (wave << 3);  // 8 rows
    const float* xp = x + (size_t)row0 * H;

    float acc[8][8];
#pragma unroll
    for (int r = 0; r < 8; ++r)
#pragma unroll
      for (int j = 0; j < 8; ++j) acc[r][j] = 0.f;

#pragma unroll 2
    for (int c = 0; c < 12; ++c) {
      const int h0 = (c << 6) + (hg << 2);
      float4 xv[8];
#pragma unroll
      for (int r = 0; r < 8; ++r)
        xv[r] = *reinterpret_cast<const float4*>(xp + r * H + h0);
#pragma unroll
      for (int j = 0; j < 8; ++j) {
        const float4 sv =
            *reinterpret_cast<const float4*>(&s_seed[(qg * 8 + j) * H + h0]);
#pragma unroll
        for (int r = 0; r < 8; ++r) {
          acc[r][j] = fmaf(xv[r].x, sv.x, acc[r][j]);
          acc[r][j] = fmaf(xv[r].y, sv.y, acc[r][j]);
          acc[r][j] = fmaf(xv[r].z, sv.z, acc[r][j]);
          acc[r][j] = fmaf(xv[r].w, sv.w, acc[r][j]);
        }
      }
    }

    // Value-splitting butterfly reduce across the 16 hg lanes.
    const bool up8 = (hg & 8) != 0;
    const bool up4 = (hg & 4) != 0;
    const bool up2 = (hg & 2) != 0;
    const bool up1 = (hg & 1) != 0;

    float t8[8][4];
#pragma unroll
    for (int r = 0; r < 8; ++r)
#pragma unroll
      for (int jj = 0; jj < 4; ++jj) {
        float send = up8 ? acc[r][jj] : acc[r][jj + 4];
        float recv = __shfl_xor(send, 8);
        float keep = up8 ? acc[r][jj + 4] : acc[r][jj];
        t8[r][jj] = keep + recv;
      }
    float t4[8][2];
#pragma unroll
    for (int r = 0; r < 8; ++r)
#pragma unroll
      for (int jj = 0; jj < 2; ++jj) {
        float send = up4 ? t8[r][jj] : t8[r][jj + 2];
        float recv = __shfl_xor(send, 4);
        float keep = up4 ? t8[r][jj + 2] : t8[r][jj];
        t4[r][jj] = keep + recv;
      }
    float t2[8];
#pragma unroll
    for (int r = 0; r < 8; ++r) {
      float send = up2 ? t4[r][0] : t4[r][1];
      float recv = __shfl_xor(send, 2);
      float keep = up2 ? t4[r][1] : t4[r][0];
      t2[r] = keep + recv;
    }
    float v4[4];
#pragma unroll
    for (int k = 0; k < 4; ++k) {
      float send = up1 ? t2[k] : t2[k + 4];
      float recv = __shfl_xor(send, 1);
      float keep = up1 ? t2[k + 4] : t2[k];
      v4[k] = keep + recv;
    }

    const int j = (hg >> 1) & 7;
    const int q = qg * 8 + j;
    const int b = row0 >> 13;
    const int n0 = (row0 & (N - 1)) + ((hg & 1) << 2);
    float4 o;
    o.x = v4[0]; o.y = v4[1]; o.z = v4[2]; o.w = v4[3];
    *reinterpret_cast<float4*>(scores + (((size_t)(b * Q + q)) << 13) + n0) = o;
  }
}

// ---------------------------------------------------------------------------
// Kernel 2: per (b,q) row: top-128 of 8192 scores -> softmax -> gather V.
// Grid 512 blocks x 512 threads. Gather: 2 k-slices x 192 threads x float4,
// partials combined through LDS.
// ---------------------------------------------------------------------------
__global__ __launch_bounds__(512) void k_topk(const float* __restrict__ scores,
                                              const float* __restrict__ x,
                                              float* __restrict__ out) {
  const int bq = blockIdx.x;
  const int b = bq >> 5;
  const int tid = threadIdx.x;
  const float* srow = scores + ((size_t)bq << 13);

  // Load 16 scores per thread; build monotonic uint keys.
  float f[16];
  uint32_t u[16];
  const float4* s4 = reinterpret_cast<const float4*>(srow);
#pragma unroll
  for (int i = 0; i < 4; ++i) {
    float4 v = s4[i * 512 + tid];
    f[i * 4 + 0] = v.x; f[i * 4 + 1] = v.y;
    f[i * 4 + 2] = v.z; f[i * 4 + 3] = v.w;
  }
#pragma unroll
  for (int e = 0; e < 16; ++e) {
    uint32_t bits = __float_as_uint(f[e]);
    u[e] = (bits & 0x80000000u) ? ~bits : (bits | 0x80000000u);
  }

  // Binary search smallest T with count(u > T) < K.
  __shared__ int s_red[8];
  uint32_t lo = 0u, hi = 0xFFFFFFFFu;
  while (lo < hi) {
    uint32_t mid = lo + ((hi - lo) >> 1);
    int cnt = 0;
#pragma unroll
    for (int e = 0; e < 16; ++e) cnt += (u[e] > mid) ? 1 : 0;
#pragma unroll
    for (int m = 1; m < 64; m <<= 1) cnt += __shfl_xor(cnt, m);
    if ((tid & 63) == 0) s_red[tid >> 6] = cnt;
    __syncthreads();
    cnt = 0;
#pragma unroll
    for (int w = 0; w < 8; ++w) cnt += s_red[w];
    if (cnt >= K) lo = mid + 1; else hi = mid;
    __syncthreads();
  }
  const uint32_t T = lo;

  // Collect strictly-greater, then lowest-index ties == T.
  __shared__ int s_cnt, s_eqn;
  __shared__ int s_idx[K];
  __shared__ float s_w[K];
  __shared__ int s_eq[256];
  __shared__ float s_m, s_sum;
  if (tid == 0) { s_cnt = 0; s_eqn = 0; }
  __syncthreads();
#pragma unroll
  for (int e = 0; e < 16; ++e) {
    int n = (((e >> 2) * 512 + tid) << 2) + (e & 3);
    if (u[e] > T) {
      int p = atomicAdd(&s_cnt, 1);
      s_idx[p] = n;
      s_w[p] = f[e];
    } else if (u[e] == T) {
      int p = atomicAdd(&s_eqn, 1);
      if (p < 256) s_eq[p] = n;
    }
  }
  __syncthreads();
  const int c1 = s_cnt;
  const int need = K - c1;
  if (tid == 0 && need > 0) {
    uint32_t tb = (T & 0x80000000u) ? (T ^ 0x80000000u) : ~T;
    float tf = __uint_as_float(tb);
    int m = s_eqn; if (m > 256) m = 256;
    for (int a = 0; a < need; ++a) {       // selection-sort lowest indices
      int best = s_eq[a], bi = a;
      for (int z = a + 1; z < m; ++z)
        if (s_eq[z] < best) { best = s_eq[z]; bi = z; }
      s_eq[bi] = s_eq[a]; s_eq[a] = best;
      s_idx[c1 + a] = best;
      s_w[c1 + a] = tf;
    }
  }
  __syncthreads();

  // Softmax over the 128 selected values (store un-normalized exp in s_w).
  if (tid < 64) {
    float v = fmaxf(s_w[tid], s_w[tid + 64]);
#pragma unroll
    for (int m = 1; m < 64; m <<= 1) v = fmaxf(v, __shfl_xor(v, m));
    if (tid == 0) s_m = v;
  }
  __syncthreads();
  const float mx = s_m * SCALE;
  if (tid < K) s_w[tid] = __expf(s_w[tid] * SCALE - mx);
  __syncthreads();
  if (tid < 64) {
    float v = s_w[tid] + s_w[tid + 64];
#pragma unroll
    for (int m = 1; m < 64; m <<= 1) v += __shfl_xor(v, m);
    if (tid == 0) s_sum = v;
  }
  __syncthreads();

  // Gather + weighted sum: 2 k-slices x 192 threads x float4 (768 floats).
  __shared__ __align__(16) float s_part[H];   // 3 KiB
  {
    const int t = tid & 255;        // lane within slice
    const int ks = tid >> 8;        // k-slice: 0 or 1
    float4 acc = make_float4(0.f, 0.f, 0.f, 0.f);
    if (t < 192) {
      const float4* xb =
          reinterpret_cast<const float4*>(x + (((size_t)b) << 13) * H);
      const int k0 = ks << 6;
#pragma unroll 4
      for (int k = k0; k < k0 + 64; ++k) {
        const float w = s_w[k];
        const float4 v = xb[(size_t)s_idx[k] * (H / 4) + t];
        acc.x = fmaf(w, v.x, acc.x);
        acc.y = fmaf(w, v.y, acc.y);
        acc.z = fmaf(w, v.z, acc.z);
        acc.w = fmaf(w, v.w, acc.w);
      }
    }
    if (ks == 0 && t < 192)
      reinterpret_cast<float4*>(s_part)[t] = acc;
    __syncthreads();
    if (ks == 1 && t < 192) {
      const float4 p = reinterpret_cast<const float4*>(s_part)[t];
      const float inv = 1.f / s_sum;
      float4 o;
      o.x = (acc.x + p.x) * inv;
      o.y = (acc.y + p.y) * inv;
      o.z = (acc.z + p.z) * inv;
      o.w = (acc.w + p.w) * inv;
      reinterpret_cast<float4*>(out)[(size_t)bq * (H / 4) + t] = o;
    }
  }
}

extern "C" void kernel_launch(void* const* d_in, const int* in_sizes, int n_in,
                              void* d_out, int out_size, void* d_ws, size_t ws_size,
                              hipStream_t stream) {
  const float* x = (const float*)d_in[0];     // [B, N, H] f32
  const float* seed = (const float*)d_in[1];  // [1, Q, H] f32
  float* out = (float*)d_out;                 // [B, Q, H] f32
  float* scores = (float*)d_ws;               // [B*Q, N] f32 = 16 MiB scratch

  k_scores<<<256, 512, 0, stream>>>(x, seed, scores);
  k_topk<<<512, 512, 0, stream>>>(scores, x, out);
}

// Round 5
// 126.374 us; speedup vs baseline: 13.7960x; 1.2243x over previous
//
#include <hip/hip_runtime.h>
#include <hip/hip_bf16.h>

// Problem constants (from reference)
constexpr int B = 16;
constexpr int N = 8192;
constexpr int H = 768;
constexpr int Q = 32;      // K_SEEDS
constexpr int K = 128;     // TOPK
#define SCALE 0.28867513459481287f   // 12^-0.5

typedef __attribute__((ext_vector_type(8))) short bf16x8_t;
typedef __attribute__((ext_vector_type(4))) float f32x4_t;

// LDS layout: xs[3 split][256 n][32 h] bf16 (row stride 64 B) + ss[3][32 q][32 h]
#define XS_OFF 0
#define XS_SPLIT 16384     // 256 rows * 64 B
#define SS_OFF 49152
#define SS_SPLIT 2048      // 32 rows * 64 B
#define LDS_BYTES 55296

__device__ __forceinline__ ushort f32_to_bf16_rn(float f) {
  uint32_t u = __float_as_uint(f);
  uint32_t r = (u + 0x7FFFu + ((u >> 16) & 1u)) >> 16;
  return (ushort)r;
}
__device__ __forceinline__ float bf16_to_f32(ushort h) {
  return __uint_as_float(((uint32_t)h) << 16);
}
// f32 -> bf16 hi/mid/lo, residuals exact (Sterbenz)
__device__ __forceinline__ void split3(float f, ushort& h, ushort& m, ushort& l) {
  h = f32_to_bf16_rn(f);
  float f1 = f - bf16_to_f32(h);
  m = f32_to_bf16_rn(f1);
  float f2 = f1 - bf16_to_f32(m);
  l = f32_to_bf16_rn(f2);
}

// swizzled frag read: 16 B at (row, 16-B sub-block l4), sub-block XOR'd by row
__device__ __forceinline__ bf16x8_t ld_frag(const char* p, int row, int l4) {
  int sb = l4 ^ ((row >> 1) & 3);
  return *reinterpret_cast<const bf16x8_t*>(p + row * 64 + (sb << 4));
}

#define MFMA(a, b, c) __builtin_amdgcn_mfma_f32_16x16x32_bf16(a, b, c, 0, 0, 0)

// Stage one 32-h chunk: split px (4 rows x 4 h) + ps (2 seed el) -> LDS
#define STAGE_CHUNK(PX, PS)                                                    \
  {                                                                            \
    _Pragma("unroll") for (int r = 0; r < 4; ++r) {                            \
      const int row = sn + r * 64;                                             \
      const int byt = sh * 2;                                                  \
      const int sb = (byt >> 4) ^ ((row >> 1) & 3);                            \
      char* dst = lds + XS_OFF + row * 64 + (sb << 4) + (byt & 15);            \
      ushort4 uh, um, ul;                                                      \
      split3(PX[r].x, uh.x, um.x, ul.x);                                       \
      split3(PX[r].y, uh.y, um.y, ul.y);                                       \
      split3(PX[r].z, uh.z, um.z, ul.z);                                       \
      split3(PX[r].w, uh.w, um.w, ul.w);                                       \
      *reinterpret_cast<ushort4*>(dst + 0 * XS_SPLIT) = uh;                    \
      *reinterpret_cast<ushort4*>(dst + 1 * XS_SPLIT) = um;                    \
      *reinterpret_cast<ushort4*>(dst + 2 * XS_SPLIT) = ul;                    \
    }                                                                          \
    {                                                                          \
      const int byt = sh2 * 2;                                                 \
      const int sb = (byt >> 4) ^ ((sq >> 1) & 3);                             \
      char* dst = lds + SS_OFF + sq * 64 + (sb << 4) + (byt & 15);             \
      ushort2 uh, um, ul;                                                      \
      split3(PS.x, uh.x, um.x, ul.x);                                          \
      split3(PS.y, uh.y, um.y, ul.y);                                          \
      *reinterpret_cast<ushort2*>(dst + 0 * SS_SPLIT) = uh;                    \
      *reinterpret_cast<ushort2*>(dst + 1 * SS_SPLIT) = um;                    \
      *reinterpret_cast<ushort2*>(dst + 2 * SS_SPLIT) = ul;                    \
    }                                                                          \
  }

// One chunk of MFMA: 12 frag reads + 24 mfma (6 passes x 4 C-tiles)
#define MFMA_CHUNK()                                                           \
  {                                                                            \
    const char* ssb = lds + SS_OFF;                                            \
    const char* xsb = lds + XS_OFF;                                            \
    bf16x8_t a0H = ld_frag(ssb + 0 * SS_SPLIT, l15, l4);                       \
    bf16x8_t a1H = ld_frag(ssb + 0 * SS_SPLIT, 16 + l15, l4);                  \
    bf16x8_t b0H = ld_frag(xsb + 0 * XS_SPLIT, nloc + l15, l4);                \
    bf16x8_t b1H = ld_frag(xsb + 0 * XS_SPLIT, nloc + 16 + l15, l4);           \
    bf16x8_t a0M = ld_frag(ssb + 1 * SS_SPLIT, l15, l4);                       \
    bf16x8_t a1M = ld_frag(ssb + 1 * SS_SPLIT, 16 + l15, l4);                  \
    bf16x8_t b0M = ld_frag(xsb + 1 * XS_SPLIT, nloc + l15, l4);                \
    bf16x8_t b1M = ld_frag(xsb + 1 * XS_SPLIT, nloc + 16 + l15, l4);           \
    bf16x8_t a0L = ld_frag(ssb + 2 * SS_SPLIT, l15, l4);                       \
    bf16x8_t a1L = ld_frag(ssb + 2 * SS_SPLIT, 16 + l15, l4);                  \
    bf16x8_t b0L = ld_frag(xsb + 2 * XS_SPLIT, nloc + l15, l4);                \
    bf16x8_t b1L = ld_frag(xsb + 2 * XS_SPLIT, nloc + 16 + l15, l4);           \
    acc00 = MFMA(a0H, b0H, acc00); acc01 = MFMA(a0H, b1H, acc01);              \
    acc10 = MFMA(a1H, b0H, acc10); acc11 = MFMA(a1H, b1H, acc11);              \
    acc00 = MFMA(a0H, b0M, acc00); acc01 = MFMA(a0H, b1M, acc01);              \
    acc10 = MFMA(a1H, b0M, acc10); acc11 = MFMA(a1H, b1M, acc11);              \
    acc00 = MFMA(a0M, b0H, acc00); acc01 = MFMA(a0M, b1H, acc01);              \
    acc10 = MFMA(a1M, b0H, acc10); acc11 = MFMA(a1M, b1H, acc11);              \
    acc00 = MFMA(a0M, b0M, acc00); acc01 = MFMA(a0M, b1M, acc01);              \
    acc10 = MFMA(a1M, b0M, acc10); acc11 = MFMA(a1M, b1M, acc11);              \
    acc00 = MFMA(a0H, b0L, acc00); acc01 = MFMA(a0H, b1L, acc01);              \
    acc10 = MFMA(a1H, b0L, acc10); acc11 = MFMA(a1H, b1L, acc11);              \
    acc00 = MFMA(a0L, b0H, acc00); acc01 = MFMA(a0L, b1H, acc01);              \
    acc10 = MFMA(a1L, b0H, acc10); acc11 = MFMA(a1L, b1H, acc11);              \
  }

// ---------------------------------------------------------------------------
// Kernel 1 (MFMA bf16x3): scores[b*Q+q][n] = dot(x[b,n,:], seed[q,:])
// Grid 512 blocks x 512 threads; block = (b = bid>>5, nb = bid&31), 256 n-rows,
// all 32 q. K-loop: 24 chunks of 32 h; reg-prefetch double buffer; 2 blocks/CU.
// ---------------------------------------------------------------------------
__global__ __launch_bounds__(512, 4) void k_scores(const float* __restrict__ x,
                                                   const float* __restrict__ seed,
                                                   float* __restrict__ scores) {
  __shared__ __align__(16) char lds[LDS_BYTES];

  const int tid = threadIdx.x;
  const int bid = blockIdx.x;
  const int b = bid >> 5;
  const int nb = bid & 31;
  const size_t xbase = ((size_t)b * N + (size_t)nb * 256) * H;

  const int lane = tid & 63;
  const int wave = tid >> 6;
  const int l15 = lane & 15;
  const int l4 = lane >> 4;
  const int nloc = wave * 32;

  // staging indices: x: thread loads rows sn + r*64 at float offset sh (4 floats)
  const int sn = tid >> 3;           // 0..63
  const int sh = (tid & 7) << 2;     // 0,4,...,28
  // seed: thread loads 2 floats at (q = sq, h = sh2)
  const int sq = tid >> 4;           // 0..31
  const int sh2 = (tid & 15) << 1;   // 0,2,...,30

  f32x4_t acc00 = {0.f, 0.f, 0.f, 0.f};
  f32x4_t acc01 = {0.f, 0.f, 0.f, 0.f};
  f32x4_t acc10 = {0.f, 0.f, 0.f, 0.f};
  f32x4_t acc11 = {0.f, 0.f, 0.f, 0.f};

  float4 pxA[4], pxB[4];
  float2 psA, psB;

  // prologue: chunk 0 -> A regs
  {
    const float* xp = x + xbase + sh;
#pragma unroll
    for (int r = 0; r < 4; ++r)
      pxA[r] = *reinterpret_cast<const float4*>(xp + (size_t)(sn + r * 64) * H);
    psA = *reinterpret_cast<const float2*>(seed + (size_t)sq * H + sh2);
  }

#pragma unroll 1
  for (int c = 0; c < 24; c += 2) {
    // prefetch chunk c+1 -> B regs (issue before consuming A)
    {
      const float* xp = x + xbase + (c + 1) * 32 + sh;
#pragma unroll
      for (int r = 0; r < 4; ++r)
        pxB[r] = *reinterpret_cast<const float4*>(xp + (size_t)(sn + r * 64) * H);
      psB = *reinterpret_cast<const float2*>(seed + (size_t)sq * H + (c + 1) * 32 + sh2);
    }
    STAGE_CHUNK(pxA, psA);
    __syncthreads();
    MFMA_CHUNK();
    __syncthreads();

    // prefetch chunk c+2 -> A regs
    if (c + 2 < 24) {
      const float* xp = x + xbase + (c + 2) * 32 + sh;
#pragma unroll
      for (int r = 0; r < 4; ++r)
        pxA[r] = *reinterpret_cast<const float4*>(xp + (size_t)(sn + r * 64) * H);
      psA = *reinterpret_cast<const float2*>(seed + (size_t)sq * H + (c + 2) * 32 + sh2);
    }
    STAGE_CHUNK(pxB, psB);
    __syncthreads();
    MFMA_CHUNK();
    __syncthreads();
  }

  // epilogue: C[q][n]: q = qt*16 + l4*4 + r, n = nloc + nt*16 + l15
  float* srow = scores + (((size_t)(b * Q)) << 13) + nb * 256 + nloc;
#pragma unroll
  for (int r = 0; r < 4; ++r) {
    srow[((size_t)(l4 * 4 + r) << 13) + l15] = acc00[r];
    srow[((size_t)(l4 * 4 + r) << 13) + 16 + l15] = acc01[r];
    srow[((size_t)(16 + l4 * 4 + r) << 13) + l15] = acc10[r];
    srow[((size_t)(16 + l4 * 4 + r) << 13) + 16 + l15] = acc11[r];
  }
}

// ---------------------------------------------------------------------------
// Kernel 2 (round-4, unchanged): per (b,q) row: top-128 -> softmax -> gather V.
// Grid 512 blocks x 512 threads.
// ---------------------------------------------------------------------------
__global__ __launch_bounds__(512) void k_topk(const float* __restrict__ scores,
                                              const float* __restrict__ x,
                                              float* __restrict__ out) {
  const int bq = blockIdx.x;
  const int b = bq >> 5;
  const int tid = threadIdx.x;
  const float* srow = scores + ((size_t)bq << 13);

  // Load 16 scores per thread; build monotonic uint keys.
  float f[16];
  uint32_t u[16];
  const float4* s4 = reinterpret_cast<const float4*>(srow);
#pragma unroll
  for (int i = 0; i < 4; ++i) {
    float4 v = s4[i * 512 + tid];
    f[i * 4 + 0] = v.x; f[i * 4 + 1] = v.y;
    f[i * 4 + 2] = v.z; f[i * 4 + 3] = v.w;
  }
#pragma unroll
  for (int e = 0; e < 16; ++e) {
    uint32_t bits = __float_as_uint(f[e]);
    u[e] = (bits & 0x80000000u) ? ~bits : (bits | 0x80000000u);
  }

  // Binary search smallest T with count(u > T) < K.
  __shared__ int s_red[8];
  uint32_t lo = 0u, hi = 0xFFFFFFFFu;
  while (lo < hi) {
    uint32_t mid = lo + ((hi - lo) >> 1);
    int cnt = 0;
#pragma unroll
    for (int e = 0; e < 16; ++e) cnt += (u[e] > mid) ? 1 : 0;
#pragma unroll
    for (int m = 1; m < 64; m <<= 1) cnt += __shfl_xor(cnt, m);
    if ((tid & 63) == 0) s_red[tid >> 6] = cnt;
    __syncthreads();
    cnt = 0;
#pragma unroll
    for (int w = 0; w < 8; ++w) cnt += s_red[w];
    if (cnt >= K) lo = mid + 1; else hi = mid;
    __syncthreads();
  }
  const uint32_t T = lo;

  // Collect strictly-greater, then lowest-index ties == T.
  __shared__ int s_cnt, s_eqn;
  __shared__ int s_idx[K];
  __shared__ float s_w[K];
  __shared__ int s_eq[256];
  __shared__ float s_m, s_sum;
  if (tid == 0) { s_cnt = 0; s_eqn = 0; }
  __syncthreads();
#pragma unroll
  for (int e = 0; e < 16; ++e) {
    int n = (((e >> 2) * 512 + tid) << 2) + (e & 3);
    if (u[e] > T) {
      int p = atomicAdd(&s_cnt, 1);
      s_idx[p] = n;
      s_w[p] = f[e];
    } else if (u[e] == T) {
      int p = atomicAdd(&s_eqn, 1);
      if (p < 256) s_eq[p] = n;
    }
  }
  __syncthreads();
  const int c1 = s_cnt;
  const int need = K - c1;
  if (tid == 0 && need > 0) {
    uint32_t tb = (T & 0x80000000u) ? (T ^ 0x80000000u) : ~T;
    float tf = __uint_as_float(tb);
    int m = s_eqn; if (m > 256) m = 256;
    for (int a = 0; a < need; ++a) {       // selection-sort lowest indices
      int best = s_eq[a], bi = a;
      for (int z = a + 1; z < m; ++z)
        if (s_eq[z] < best) { best = s_eq[z]; bi = z; }
      s_eq[bi] = s_eq[a]; s_eq[a] = best;
      s_idx[c1 + a] = best;
      s_w[c1 + a] = tf;
    }
  }
  __syncthreads();

  // Softmax over the 128 selected values (store un-normalized exp in s_w).
  if (tid < 64) {
    float v = fmaxf(s_w[tid], s_w[tid + 64]);
#pragma unroll
    for (int m = 1; m < 64; m <<= 1) v = fmaxf(v, __shfl_xor(v, m));
    if (tid == 0) s_m = v;
  }
  __syncthreads();
  const float mx = s_m * SCALE;
  if (tid < K) s_w[tid] = __expf(s_w[tid] * SCALE - mx);
  __syncthreads();
  if (tid < 64) {
    float v = s_w[tid] + s_w[tid + 64];
#pragma unroll
    for (int m = 1; m < 64; m <<= 1) v += __shfl_xor(v, m);
    if (tid == 0) s_sum = v;
  }
  __syncthreads();

  // Gather + weighted sum: 2 k-slices x 192 threads x float4 (768 floats).
  __shared__ __align__(16) float s_part[H];   // 3 KiB
  {
    const int t = tid & 255;        // lane within slice
    const int ks = tid >> 8;        // k-slice: 0 or 1
    float4 acc = make_float4(0.f, 0.f, 0.f, 0.f);
    if (t < 192) {
      const float4* xb =
          reinterpret_cast<const float4*>(x + (((size_t)b) << 13) * H);
      const int k0 = ks << 6;
#pragma unroll 4
      for (int k = k0; k < k0 + 64; ++k) {
        const float w = s_w[k];
        const float4 v = xb[(size_t)s_idx[k] * (H / 4) + t];
        acc.x = fmaf(w, v.x, acc.x);
        acc.y = fmaf(w, v.y, acc.y);
        acc.z = fmaf(w, v.z, acc.z);
        acc.w = fmaf(w, v.w, acc.w);
      }
    }
    if (ks == 0 && t < 192)
      reinterpret_cast<float4*>(s_part)[t] = acc;
    __syncthreads();
    if (ks == 1 && t < 192) {
      const float4 p = reinterpret_cast<const float4*>(s_part)[t];
      const float inv = 1.f / s_sum;
      float4 o;
      o.x = (acc.x + p.x) * inv;
      o.y = (acc.y + p.y) * inv;
      o.z = (acc.z + p.z) * inv;
      o.w = (acc.w + p.w) * inv;
      reinterpret_cast<float4*>(out)[(size_t)bq * (H / 4) + t] = o;
    }
  }
}

extern "C" void kernel_launch(void* const* d_in, const int* in_sizes, int n_in,
                              void* d_out, int out_size, void* d_ws, size_t ws_size,
                              hipStream_t stream) {
  const float* x = (const float*)d_in[0];     // [B, N, H] f32
  const float* seed = (const float*)d_in[1];  // [1, Q, H] f32
  float* out = (float*)d_out;                 // [B, Q, H] f32
  float* scores = (float*)d_ws;               // [B*Q, N] f32 = 16 MiB scratch

  k_scores<<<512, 512, 0, stream>>>(x, seed, scores);
  k_topk<<<512, 512, 0, stream>>>(scores, x, out);
}